// Round 15
// baseline (197.764 us; speedup 1.0000x reference)
//
#include <hip/hip_runtime.h>
#include <stdint.h>
#include <math.h>

#define BSZ 4096
#define DIM 768
#define TEMP 0.07f

typedef short short8 __attribute__((ext_vector_type(8)));
typedef short short4v __attribute__((ext_vector_type(4)));
typedef float f32x4 __attribute__((ext_vector_type(4)));

// ---------- helpers ----------

__device__ __forceinline__ uint16_t f2bf(float f) {
  uint32_t u = __float_as_uint(f);
  uint32_t r = (u + 0x7FFFu + ((u >> 16) & 1u)) >> 16;  // RNE
  return (uint16_t)r;
}

__device__ __forceinline__ void gll16(const void* g, void* l) {
  __builtin_amdgcn_global_load_lds(
      (__attribute__((address_space(1))) void*)(uintptr_t)g,
      (__attribute__((address_space(3))) void*)l,
      16, 0, 0);
}

// branchy sorted-desc top-5 insert (kept for tiny k_merge only)
__device__ __forceinline__ void ins5(float v, float& a, float& b, float& c,
                                     float& d, float& e) {
  if (v > e) {
    e = v;
    if (e > d) { float t = d; d = e; e = t;
      if (d > c) { t = c; c = d; d = t;
        if (c > b) { t = b; b = c; c = t;
          if (b > a) { t = a; a = b; b = t; } } } }
  }
}

// branchless sorted-desc top-5 insert: 9 v_min/v_max, no divergence
__device__ __forceinline__ void sins5(float v, float& a, float& b, float& c,
                                      float& d, float& e) {
  float t;
  t = fmaxf(a, v); v = fminf(a, v); a = t;
  t = fmaxf(b, v); v = fminf(b, v); b = t;
  t = fmaxf(c, v); v = fminf(c, v); c = t;
  t = fmaxf(d, v); v = fminf(d, v); d = t;
  e = fmaxf(e, v);
}

// ---------- K1: normalize + cast to bf16 (f32x4 loads, short4 stores) ----------
// Block 0 also zeroes the k_merge completion counter (stream-ordered upstream).
__global__ __launch_bounds__(192) void k_norm(const float* __restrict__ text,
                                              const float* __restrict__ table,
                                              uint16_t* __restrict__ tn,
                                              uint16_t* __restrict__ zn,
                                              unsigned* __restrict__ ctr) {
  if (blockIdx.x == 0 && threadIdx.x == 0) ctr[0] = 0u;
  int row = blockIdx.x & (BSZ - 1);
  bool isTable = blockIdx.x >= BSZ;
  const float* src = (isTable ? table : text) + (size_t)row * DIM;
  uint16_t* dst = (isTable ? zn : tn) + (size_t)row * DIM;
  int tid = threadIdx.x;

  f32x4 v = *(const f32x4*)(src + tid * 4);
  float ss = v[0] * v[0] + v[1] * v[1] + v[2] * v[2] + v[3] * v[3];
  #pragma unroll
  for (int off = 32; off >= 1; off >>= 1) ss += __shfl_xor(ss, off);
  __shared__ float wss[3];
  if ((tid & 63) == 0) wss[tid >> 6] = ss;
  __syncthreads();
  float inv = rsqrtf(wss[0] + wss[1] + wss[2]);
  short4v o;
  o[0] = (short)f2bf(v[0] * inv);
  o[1] = (short)f2bf(v[1] * inv);
  o[2] = (short)f2bf(v[2] * inv);
  o[3] = (short)f2bf(v[3] * inv);
  *(short4v*)(dst + tid * 4) = o;
}

// ---------- K2: sim = Zn @ Tn^T  (2 barriers/K-tile; no setprio — T5/m190:
// null-to-negative on lockstep non-phase-split GEMM structures) ---------------
// 256x256 tile, BK=64, 8 waves (2M x 4N), coalesced staging + XOR-swizzled
// 128B-row LDS, XCD-chunked block mapping (4x8 tile region/XCD ~ L2).
// Per K-tile: {LOADB + PHASE0 + PHASE4 (24 ds_read, 64 MFMA) ; barrier ;
// stage all 8 gll16 for tile t+2 into this buffer (all regions dead) ;
// vmcnt(8) retires tile t+1's 8 loads (per-wave) ; barrier}.
// Queue invariant: 8 loads outstanding at every tile boundary; never drained.
__global__ __launch_bounds__(512, 2) void k_gemm(const uint16_t* __restrict__ Zb,
                                                 const uint16_t* __restrict__ Tb,
                                                 float* __restrict__ sim) {
  extern __shared__ __attribute__((aligned(16))) char lds[];

  int tid = threadIdx.x;
  int wave = tid >> 6, lane = tid & 63;
  int wm = wave >> 2, wn = wave & 3;

  // XCD-chunked mapping: xcd = bid&7 owns tile rows [4*(xcd>>1),+4) x cols [8*(xcd&1),+8).
  int bid = blockIdx.x;
  int xcd = bid & 7, li = bid >> 3;
  int brow = (((xcd >> 1) << 2) + (li >> 3)) << 8;
  int bcol = (((xcd & 1) << 3) + (li & 7)) << 8;

  f32x4 acc[8][4] = {};

  const uint16_t* gA = Zb + (size_t)brow * DIM;
  const uint16_t* gB = Tb + (size_t)bcol * DIM;

  int r7 = lane & 7;
  int kqg = lane >> 4;    // 0..3
  int rlo = lane & 15;

  int srow = (wave << 5) + (lane >> 3);
  int sc = ((lane & 7) ^ (srow & 7)) << 3;   // uint16 offset of permuted chunk

  auto SA = [&](int t, int bb, int j) {
    gll16(gA + (size_t)(srow + j * 8) * DIM + t * 64 + sc,
          lds + bb + (wave << 12) + (j << 10));
  };
  auto SB = [&](int t, int bb, int j) {
    gll16(gB + (size_t)(srow + j * 8) * DIM + t * 64 + sc,
          lds + bb + 32768 + (wave << 12) + (j << 10));
  };

  auto LOADB = [&](int bb, short8 (&bf)[2][4]) {
    const char* Bb = lds + bb + 32768;
    #pragma unroll
    for (int ks = 0; ks < 2; ++ks) {
      int ch = (((ks << 2) + kqg) ^ r7) << 4;
      #pragma unroll
      for (int n = 0; n < 4; ++n) {
        int R = (wn << 6) + (n << 4) + rlo;
        bf[ks][n] = *(const short8*)(Bb + (R << 7) + ch);
      }
    }
  };
  auto PHASE = [&](int bb, int mlo, short8 (&bf)[2][4]) {
    #pragma unroll
    for (int ks = 0; ks < 2; ++ks) {
      int ch = (((ks << 2) + kqg) ^ r7) << 4;
      #pragma unroll
      for (int mm = 0; mm < 4; ++mm) {
        int R = (wm << 7) + ((mlo + mm) << 4) + rlo;
        short8 af = *(const short8*)(lds + bb + (R << 7) + ch);
        #pragma unroll
        for (int n = 0; n < 4; ++n)
          acc[mlo + mm][n] = __builtin_amdgcn_mfma_f32_16x16x32_bf16(
              af, bf[ks][n], acc[mlo + mm][n], 0, 0, 0);
      }
    }
  };

  // ---- prologue: stage tiles 0 (buf0) and 1 (buf1); land 0, keep 1 in flight
  #pragma unroll
  for (int j = 0; j < 4; ++j) { SA(0, 0, j); SB(0, 0, j); }
  #pragma unroll
  for (int j = 0; j < 4; ++j) { SA(1, 65536, j); SB(1, 65536, j); }
  asm volatile("s_waitcnt vmcnt(8)" ::: "memory");
  __builtin_amdgcn_s_barrier();

  // ---- main loop: tiles 0..9, staging tiles 2..11 (8 gll16/wave/tile)
  #pragma unroll 2
  for (int t = 0; t < 10; ++t) {
    int bb = (t & 1) << 16;
    short8 bf[2][4];
    LOADB(bb, bf);
    PHASE(bb, 0, bf);
    PHASE(bb, 4, bf);
    __builtin_amdgcn_s_barrier();            // all reads of buffer bb done
    SA(t + 2, bb, 0); SA(t + 2, bb, 1); SA(t + 2, bb, 2); SA(t + 2, bb, 3);
    SB(t + 2, bb, 0); SB(t + 2, bb, 1); SB(t + 2, bb, 2); SB(t + 2, bb, 3);
    asm volatile("s_waitcnt vmcnt(8)" ::: "memory");  // retire tile t+1's 8 loads
    __builtin_amdgcn_s_barrier();
  }

  // ---- epilogue tiles: 10 (buf0), 11 (buf1) — no further staging
  {
    short8 bf[2][4];
    LOADB(0, bf);
    PHASE(0, 0, bf);
    PHASE(0, 4, bf);
  }
  asm volatile("s_waitcnt vmcnt(0)" ::: "memory");
  __builtin_amdgcn_s_barrier();
  {
    short8 bf[2][4];
    LOADB(65536, bf);
    PHASE(65536, 0, bf);
    PHASE(65536, 4, bf);
  }

  // epilogue: C/D layout col=lane&15, row=(lane>>4)*4+reg
  int crow0 = brow + (wm << 7) + ((lane >> 4) << 2);
  int ccol0 = bcol + (wn << 6) + (lane & 15);
  #pragma unroll
  for (int m = 0; m < 8; ++m)
    #pragma unroll
    for (int n = 0; n < 4; ++n)
      #pragma unroll
      for (int r = 0; r < 4; ++r)
        sim[(size_t)(crow0 + m * 16 + r) * BSZ + (ccol0 + n * 16)] = acc[m][n][r];
}

// ---------- K3: tile pass — row & col partial top-5 --------------------------
// 64x128 tile, 32 KiB LDS -> 4 blocks/CU. 2048 blocks.
// XCD-affinity matches the gemm writer mapping.
__global__ __launch_bounds__(256) void k_tile(const float* __restrict__ sim,
                                              float* __restrict__ rp,
                                              float* __restrict__ cp) {
  extern __shared__ float l32[];  // 64*128 floats = 32 KiB
  int tid = threadIdx.x;

  int xcd = blockIdx.x & 7, li = blockIdx.x >> 3;  // li 0..255
  int tr = ((xcd >> 1) << 4) + (li >> 4);   // 0..63
  int tc = ((xcd & 1) << 4) + (li & 15);    // 0..31
  int row0 = tr << 6, col0 = tc << 7;
  bool diag = ((tr >> 1) == tc);
  int lcbase = (tr & 1) << 6;   // local col of global row r when diag

  // ---- stage: 8 x f32x4 coalesced loads (rows g*8..g*8+7, col quad q)
  int q = tid & 31;   // col quad 0..31
  int g = tid >> 5;   // row group 0..7
  const float* gsrc = sim + (size_t)(row0 + (g << 3)) * BSZ + col0 + (q << 2);

  f32x4 v[8];
  #pragma unroll
  for (int k = 0; k < 8; ++k)
    v[k] = *(const f32x4*)(gsrc + (size_t)k * BSZ);

  #pragma unroll
  for (int k = 0; k < 8; ++k) {
    int r = (g << 3) + k;
    int lc = lcbase + r;
    if (diag && (lc >> 2) == q) v[k][lc & 3] = -1e30f;  // mask diagonal
    *(f32x4*)(l32 + (r << 7) + ((q ^ (r & 7)) << 2)) = v[k];
  }
  __syncthreads();

  // ---- row scan: 4 threads/row, 32 cols each via 8 x b128
  {
    int row = tid >> 2, h = tid & 3;
    int rx = row & 7;
    const float* rb = l32 + (row << 7);
    float a0 = -1e30f, a1 = -1e30f, a2 = -1e30f, a3 = -1e30f, a4 = -1e30f;
    #pragma unroll
    for (int j = 0; j < 8; ++j) {
      int c16 = (h << 3) + j;
      f32x4 x = *(const f32x4*)(rb + ((c16 ^ rx) << 2));
      sins5(x[0], a0, a1, a2, a3, a4);
      sins5(x[1], a0, a1, a2, a3, a4);
      sins5(x[2], a0, a1, a2, a3, a4);
      sins5(x[3], a0, a1, a2, a3, a4);
    }
    #pragma unroll
    for (int xr = 1; xr <= 2; xr <<= 1) {
      float b0 = __shfl_xor(a0, xr), b1 = __shfl_xor(a1, xr),
            b2 = __shfl_xor(a2, xr), b3 = __shfl_xor(a3, xr),
            b4 = __shfl_xor(a4, xr);
      sins5(b0, a0, a1, a2, a3, a4);
      sins5(b1, a0, a1, a2, a3, a4);
      sins5(b2, a0, a1, a2, a3, a4);
      sins5(b3, a0, a1, a2, a3, a4);
      sins5(b4, a0, a1, a2, a3, a4);
    }
    if (h == 0) {
      float* pr = rp + ((size_t)(row0 + row) * 32 + tc) * 5;
      pr[0] = a0; pr[1] = a1; pr[2] = a2; pr[3] = a3; pr[4] = a4;
    }
  }

  // ---- col scan: 2 threads/col, 32 rows each via b32 (read-only, no barrier)
  {
    int c = tid >> 1, hf = tid & 1;
    int cc = c >> 2, cw = c & 3;
    float a0 = -1e30f, a1 = -1e30f, a2 = -1e30f, a3 = -1e30f, a4 = -1e30f;
    #pragma unroll 8
    for (int k = 0; k < 32; ++k) {
      int r = (hf << 5) + k;
      float x = l32[(r << 7) + (((cc ^ (r & 7)) << 2) | cw)];
      sins5(x, a0, a1, a2, a3, a4);
    }
    float b0 = __shfl_xor(a0, 1), b1 = __shfl_xor(a1, 1),
          b2 = __shfl_xor(a2, 1), b3 = __shfl_xor(a3, 1),
          b4 = __shfl_xor(a4, 1);
    sins5(b0, a0, a1, a2, a3, a4);
    sins5(b1, a0, a1, a2, a3, a4);
    sins5(b2, a0, a1, a2, a3, a4);
    sins5(b3, a0, a1, a2, a3, a4);
    sins5(b4, a0, a1, a2, a3, a4);
    if (hf == 0) {
      float* pc = cp + ((size_t)(col0 + c) * 64 + tr) * 5;
      pc[0] = a0; pc[1] = a1; pc[2] = a2; pc[3] = a3; pc[4] = a4;
    }
  }
}

// ---------- K4: merge partials + loss + last-block final reduction ----------
// rows: 32 partials (160 floats); cols: 64 partials (320 floats).
// Per-line loss -> lossbuf; fence+counter; the LAST block to finish reduces
// all 2*BSZ entries and writes out[0] (k_reduce launch eliminated).
__global__ __launch_bounds__(256) void k_merge(const float* __restrict__ sim,
                                               const float* __restrict__ rp,
                                               const float* __restrict__ cp,
                                               float* __restrict__ lossbuf,
                                               unsigned* __restrict__ ctr,
                                               float* __restrict__ out) {
  int wave = threadIdx.x >> 6, lane = threadIdx.x & 63;
  int wid = blockIdx.x * 4 + wave;
  bool isCol = wid >= BSZ;
  int line = isCol ? wid - BSZ : wid;

  float t0 = -1e30f, t1 = -1e30f, t2 = -1e30f, t3 = -1e30f, t4 = -1e30f;
  if (isCol) {
    const float* src = cp + (size_t)line * 320;
    ins5(src[lane], t0, t1, t2, t3, t4);
    ins5(src[lane + 64], t0, t1, t2, t3, t4);
    ins5(src[lane + 128], t0, t1, t2, t3, t4);
    ins5(src[lane + 192], t0, t1, t2, t3, t4);
    ins5(src[lane + 256], t0, t1, t2, t3, t4);
  } else {
    const float* src = rp + (size_t)line * 160;
    ins5(src[lane], t0, t1, t2, t3, t4);
    ins5(src[lane + 64], t0, t1, t2, t3, t4);
    if (lane < 32) ins5(src[lane + 128], t0, t1, t2, t3, t4);
  }

  float top[5];
  #pragma unroll
  for (int e = 0; e < 5; e++) {
    float m = t0;
    #pragma unroll
    for (int off = 32; off >= 1; off >>= 1) m = fmaxf(m, __shfl_xor(m, off));
    unsigned long long msk = __ballot(t0 == m);
    int owner = __ffsll(msk) - 1;
    if (lane == owner) { t0 = t1; t1 = t2; t2 = t3; t3 = t4; t4 = -1e30f; }
    top[e] = m;
  }

  if (lane == 0) {
    float pos = sim[(size_t)line * BSZ + line] / TEMP;
    float l0 = top[0] / TEMP, l1 = top[1] / TEMP, l2 = top[2] / TEMP,
          l3 = top[3] / TEMP, l4 = top[4] / TEMP;
    float mx = fmaxf(pos, fmaxf(fmaxf(l0, l1), fmaxf(fmaxf(l2, l3), l4)));
    float s = expf(pos - mx) + expf(l0 - mx) + expf(l1 - mx) +
              expf(l2 - mx) + expf(l3 - mx) + expf(l4 - mx);
    lossbuf[wid] = mx + logf(s) - pos;
  }

  // ---- last-block reduction (CUDA threadfenceReduction pattern, G16-safe)
  __shared__ bool amLast;
  __threadfence();               // make this block's lossbuf writes visible
  __syncthreads();
  if (threadIdx.x == 0) {
    unsigned prev = atomicAdd(ctr, 1u);
    amLast = (prev == gridDim.x - 1);
  }
  __syncthreads();
  if (amLast) {
    __threadfence();             // acquire: all blocks' writes visible
    int tid = threadIdx.x;
    float s = 0.f;
    for (int i = tid; i < 2 * BSZ; i += 256) s += lossbuf[i];
    #pragma unroll
    for (int off = 32; off >= 1; off >>= 1) s += __shfl_xor(s, off);
    __shared__ float wss[4];
    if ((tid & 63) == 0) wss[tid >> 6] = s;
    __syncthreads();
    if (tid == 0) out[0] = (wss[0] + wss[1] + wss[2] + wss[3]) / (2.0f * BSZ);
  }
}

// ---------- launcher ----------
extern "C" void kernel_launch(void* const* d_in, const int* in_sizes, int n_in,
                              void* d_out, int out_size, void* d_ws, size_t ws_size,
                              hipStream_t stream) {
  const float* text = (const float*)d_in[0];
  const float* table = (const float*)d_in[1];
  float* out = (float*)d_out;
  float* sim = out + 1;  // d_out = [loss, sim(4096x4096)]

  uint16_t* Zb = (uint16_t*)d_ws;
  uint16_t* Tb = Zb + (size_t)BSZ * DIM;
  float* lossbuf = (float*)(Tb + (size_t)BSZ * DIM);  // 2*BSZ floats
  unsigned* ctr = (unsigned*)(lossbuf + 2 * BSZ);

  // rp/cp alias the Zb/Tb region (dead after k_gemm; stream-ordered).
  float* rp = (float*)d_ws;                  // [4096][32][5]
  float* cp = rp + (size_t)BSZ * 32 * 5;     // [4096][64][5]

  k_norm<<<2 * BSZ, 192, 0, stream>>>(text, table, Tb, Zb, ctr);
  k_gemm<<<(BSZ / 256) * (BSZ / 256), 512, 131072, stream>>>(Zb, Tb, sim);
  k_tile<<<(BSZ / 64) * (BSZ / 128), 256, 32768, stream>>>(sim, rp, cp);
  k_merge<<<2 * BSZ / 4, 256, 0, stream>>>(sim, rp, cp, lossbuf, ctr, out);
}

// Round 16
// 77.249 us; speedup vs baseline: 2.5601x; 2.5601x over previous
//
#include <hip/hip_runtime.h>
#include <stdint.h>
#include <math.h>

#define BSZ 4096
#define DIM 768
#define TEMP 0.07f

typedef short short8 __attribute__((ext_vector_type(8)));
typedef short short4v __attribute__((ext_vector_type(4)));
typedef float f32x4 __attribute__((ext_vector_type(4)));

// ---------- helpers ----------

__device__ __forceinline__ uint16_t f2bf(float f) {
  uint32_t u = __float_as_uint(f);
  uint32_t r = (u + 0x7FFFu + ((u >> 16) & 1u)) >> 16;  // RNE
  return (uint16_t)r;
}

__device__ __forceinline__ void gll16(const void* g, void* l) {
  __builtin_amdgcn_global_load_lds(
      (__attribute__((address_space(1))) void*)(uintptr_t)g,
      (__attribute__((address_space(3))) void*)l,
      16, 0, 0);
}

// branchy sorted-desc top-5 insert (kept for tiny k_merge only)
__device__ __forceinline__ void ins5(float v, float& a, float& b, float& c,
                                     float& d, float& e) {
  if (v > e) {
    e = v;
    if (e > d) { float t = d; d = e; e = t;
      if (d > c) { t = c; c = d; d = t;
        if (c > b) { t = b; b = c; c = t;
          if (b > a) { t = a; a = b; b = t; } } } }
  }
}

// branchless sorted-desc top-5 insert: 9 v_min/v_max, no divergence
__device__ __forceinline__ void sins5(float v, float& a, float& b, float& c,
                                      float& d, float& e) {
  float t;
  t = fmaxf(a, v); v = fminf(a, v); a = t;
  t = fmaxf(b, v); v = fminf(b, v); b = t;
  t = fmaxf(c, v); v = fminf(c, v); c = t;
  t = fmaxf(d, v); v = fminf(d, v); d = t;
  e = fmaxf(e, v);
}

// ---------- K1: normalize + cast to bf16 (f32x4 loads, short4 stores) ----------
__global__ __launch_bounds__(192) void k_norm(const float* __restrict__ text,
                                              const float* __restrict__ table,
                                              uint16_t* __restrict__ tn,
                                              uint16_t* __restrict__ zn) {
  int row = blockIdx.x & (BSZ - 1);
  bool isTable = blockIdx.x >= BSZ;
  const float* src = (isTable ? table : text) + (size_t)row * DIM;
  uint16_t* dst = (isTable ? zn : tn) + (size_t)row * DIM;
  int tid = threadIdx.x;

  f32x4 v = *(const f32x4*)(src + tid * 4);
  float ss = v[0] * v[0] + v[1] * v[1] + v[2] * v[2] + v[3] * v[3];
  #pragma unroll
  for (int off = 32; off >= 1; off >>= 1) ss += __shfl_xor(ss, off);
  __shared__ float wss[3];
  if ((tid & 63) == 0) wss[tid >> 6] = ss;
  __syncthreads();
  float inv = rsqrtf(wss[0] + wss[1] + wss[2]);
  short4v o;
  o[0] = (short)f2bf(v[0] * inv);
  o[1] = (short)f2bf(v[1] * inv);
  o[2] = (short)f2bf(v[2] * inv);
  o[3] = (short)f2bf(v[3] * inv);
  *(short4v*)(dst + tid * 4) = o;
}

// ---------- K2: sim = Zn @ Tn^T  (2 barriers/K-tile; setprio removed —
// T5/m190: null-to-negative on lockstep non-phase-split GEMM structures) ------
// 256x256 tile, BK=64, 8 waves (2M x 4N), coalesced staging + XOR-swizzled
// 128B-row LDS, XCD-chunked block mapping (4x8 tile region/XCD ~ L2).
// Per K-tile: {LOADB + PHASE0 + PHASE4 (24 ds_read, 64 MFMA) ; barrier ;
// stage all 8 gll16 for tile t+2 into this buffer (all regions dead) ;
// vmcnt(8) retires tile t+1's 8 loads (per-wave) ; barrier}.
// Queue invariant: 8 loads outstanding at every tile boundary; never drained.
__global__ __launch_bounds__(512, 2) void k_gemm(const uint16_t* __restrict__ Zb,
                                                 const uint16_t* __restrict__ Tb,
                                                 float* __restrict__ sim) {
  extern __shared__ __attribute__((aligned(16))) char lds[];

  int tid = threadIdx.x;
  int wave = tid >> 6, lane = tid & 63;
  int wm = wave >> 2, wn = wave & 3;

  // XCD-chunked mapping: xcd = bid&7 owns tile rows [4*(xcd>>1),+4) x cols [8*(xcd&1),+8).
  int bid = blockIdx.x;
  int xcd = bid & 7, li = bid >> 3;
  int brow = (((xcd >> 1) << 2) + (li >> 3)) << 8;
  int bcol = (((xcd & 1) << 3) + (li & 7)) << 8;

  f32x4 acc[8][4] = {};

  const uint16_t* gA = Zb + (size_t)brow * DIM;
  const uint16_t* gB = Tb + (size_t)bcol * DIM;

  int r7 = lane & 7;
  int kqg = lane >> 4;    // 0..3
  int rlo = lane & 15;

  int srow = (wave << 5) + (lane >> 3);
  int sc = ((lane & 7) ^ (srow & 7)) << 3;   // uint16 offset of permuted chunk

  auto SA = [&](int t, int bb, int j) {
    gll16(gA + (size_t)(srow + j * 8) * DIM + t * 64 + sc,
          lds + bb + (wave << 12) + (j << 10));
  };
  auto SB = [&](int t, int bb, int j) {
    gll16(gB + (size_t)(srow + j * 8) * DIM + t * 64 + sc,
          lds + bb + 32768 + (wave << 12) + (j << 10));
  };

  auto LOADB = [&](int bb, short8 (&bf)[2][4]) {
    const char* Bb = lds + bb + 32768;
    #pragma unroll
    for (int ks = 0; ks < 2; ++ks) {
      int ch = (((ks << 2) + kqg) ^ r7) << 4;
      #pragma unroll
      for (int n = 0; n < 4; ++n) {
        int R = (wn << 6) + (n << 4) + rlo;
        bf[ks][n] = *(const short8*)(Bb + (R << 7) + ch);
      }
    }
  };
  auto PHASE = [&](int bb, int mlo, short8 (&bf)[2][4]) {
    #pragma unroll
    for (int ks = 0; ks < 2; ++ks) {
      int ch = (((ks << 2) + kqg) ^ r7) << 4;
      #pragma unroll
      for (int mm = 0; mm < 4; ++mm) {
        int R = (wm << 7) + ((mlo + mm) << 4) + rlo;
        short8 af = *(const short8*)(lds + bb + (R << 7) + ch);
        #pragma unroll
        for (int n = 0; n < 4; ++n)
          acc[mlo + mm][n] = __builtin_amdgcn_mfma_f32_16x16x32_bf16(
              af, bf[ks][n], acc[mlo + mm][n], 0, 0, 0);
      }
    }
  };

  // ---- prologue: stage tiles 0 (buf0) and 1 (buf1); land 0, keep 1 in flight
  #pragma unroll
  for (int j = 0; j < 4; ++j) { SA(0, 0, j); SB(0, 0, j); }
  #pragma unroll
  for (int j = 0; j < 4; ++j) { SA(1, 65536, j); SB(1, 65536, j); }
  asm volatile("s_waitcnt vmcnt(8)" ::: "memory");
  __builtin_amdgcn_s_barrier();

  // ---- main loop: tiles 0..9, staging tiles 2..11 (8 gll16/wave/tile)
  #pragma unroll 2
  for (int t = 0; t < 10; ++t) {
    int bb = (t & 1) << 16;
    short8 bf[2][4];
    LOADB(bb, bf);
    PHASE(bb, 0, bf);
    PHASE(bb, 4, bf);
    __builtin_amdgcn_s_barrier();            // all reads of buffer bb done
    SA(t + 2, bb, 0); SA(t + 2, bb, 1); SA(t + 2, bb, 2); SA(t + 2, bb, 3);
    SB(t + 2, bb, 0); SB(t + 2, bb, 1); SB(t + 2, bb, 2); SB(t + 2, bb, 3);
    asm volatile("s_waitcnt vmcnt(8)" ::: "memory");  // retire tile t+1's 8 loads
    __builtin_amdgcn_s_barrier();
  }

  // ---- epilogue tiles: 10 (buf0), 11 (buf1) — no further staging
  {
    short8 bf[2][4];
    LOADB(0, bf);
    PHASE(0, 0, bf);
    PHASE(0, 4, bf);
  }
  asm volatile("s_waitcnt vmcnt(0)" ::: "memory");
  __builtin_amdgcn_s_barrier();
  {
    short8 bf[2][4];
    LOADB(65536, bf);
    PHASE(65536, 0, bf);
    PHASE(65536, 4, bf);
  }

  // epilogue: C/D layout col=lane&15, row=(lane>>4)*4+reg
  int crow0 = brow + (wm << 7) + ((lane >> 4) << 2);
  int ccol0 = bcol + (wn << 6) + (lane & 15);
  #pragma unroll
  for (int m = 0; m < 8; ++m)
    #pragma unroll
    for (int n = 0; n < 4; ++n)
      #pragma unroll
      for (int r = 0; r < 4; ++r)
        sim[(size_t)(crow0 + m * 16 + r) * BSZ + (ccol0 + n * 16)] = acc[m][n][r];
}

// ---------- K3: tile pass — row & col partial top-5 --------------------------
// 64x128 tile, 32 KiB LDS -> 4 blocks/CU. 2048 blocks.
// XCD-affinity matches the gemm writer mapping.
__global__ __launch_bounds__(256) void k_tile(const float* __restrict__ sim,
                                              float* __restrict__ rp,
                                              float* __restrict__ cp) {
  extern __shared__ float l32[];  // 64*128 floats = 32 KiB
  int tid = threadIdx.x;

  int xcd = blockIdx.x & 7, li = blockIdx.x >> 3;  // li 0..255
  int tr = ((xcd >> 1) << 4) + (li >> 4);   // 0..63
  int tc = ((xcd & 1) << 4) + (li & 15);    // 0..31
  int row0 = tr << 6, col0 = tc << 7;
  bool diag = ((tr >> 1) == tc);
  int lcbase = (tr & 1) << 6;   // local col of global row r when diag

  // ---- stage: 8 x f32x4 coalesced loads (rows g*8..g*8+7, col quad q)
  int q = tid & 31;   // col quad 0..31
  int g = tid >> 5;   // row group 0..7
  const float* gsrc = sim + (size_t)(row0 + (g << 3)) * BSZ + col0 + (q << 2);

  f32x4 v[8];
  #pragma unroll
  for (int k = 0; k < 8; ++k)
    v[k] = *(const f32x4*)(gsrc + (size_t)k * BSZ);

  #pragma unroll
  for (int k = 0; k < 8; ++k) {
    int r = (g << 3) + k;
    int lc = lcbase + r;
    if (diag && (lc >> 2) == q) v[k][lc & 3] = -1e30f;  // mask diagonal
    *(f32x4*)(l32 + (r << 7) + ((q ^ (r & 7)) << 2)) = v[k];
  }
  __syncthreads();

  // ---- row scan: 4 threads/row, 32 cols each via 8 x b128
  {
    int row = tid >> 2, h = tid & 3;
    int rx = row & 7;
    const float* rb = l32 + (row << 7);
    float a0 = -1e30f, a1 = -1e30f, a2 = -1e30f, a3 = -1e30f, a4 = -1e30f;
    #pragma unroll
    for (int j = 0; j < 8; ++j) {
      int c16 = (h << 3) + j;
      f32x4 x = *(const f32x4*)(rb + ((c16 ^ rx) << 2));
      sins5(x[0], a0, a1, a2, a3, a4);
      sins5(x[1], a0, a1, a2, a3, a4);
      sins5(x[2], a0, a1, a2, a3, a4);
      sins5(x[3], a0, a1, a2, a3, a4);
    }
    #pragma unroll
    for (int xr = 1; xr <= 2; xr <<= 1) {
      float b0 = __shfl_xor(a0, xr), b1 = __shfl_xor(a1, xr),
            b2 = __shfl_xor(a2, xr), b3 = __shfl_xor(a3, xr),
            b4 = __shfl_xor(a4, xr);
      sins5(b0, a0, a1, a2, a3, a4);
      sins5(b1, a0, a1, a2, a3, a4);
      sins5(b2, a0, a1, a2, a3, a4);
      sins5(b3, a0, a1, a2, a3, a4);
      sins5(b4, a0, a1, a2, a3, a4);
    }
    if (h == 0) {
      float* pr = rp + ((size_t)(row0 + row) * 32 + tc) * 5;
      pr[0] = a0; pr[1] = a1; pr[2] = a2; pr[3] = a3; pr[4] = a4;
    }
  }

  // ---- col scan: 2 threads/col, 32 rows each via b32 (read-only, no barrier)
  {
    int c = tid >> 1, hf = tid & 1;
    int cc = c >> 2, cw = c & 3;
    float a0 = -1e30f, a1 = -1e30f, a2 = -1e30f, a3 = -1e30f, a4 = -1e30f;
    #pragma unroll 8
    for (int k = 0; k < 32; ++k) {
      int r = (hf << 5) + k;
      float x = l32[(r << 7) + (((cc ^ (r & 7)) << 2) | cw)];
      sins5(x, a0, a1, a2, a3, a4);
    }
    float b0 = __shfl_xor(a0, 1), b1 = __shfl_xor(a1, 1),
          b2 = __shfl_xor(a2, 1), b3 = __shfl_xor(a3, 1),
          b4 = __shfl_xor(a4, 1);
    sins5(b0, a0, a1, a2, a3, a4);
    sins5(b1, a0, a1, a2, a3, a4);
    sins5(b2, a0, a1, a2, a3, a4);
    sins5(b3, a0, a1, a2, a3, a4);
    sins5(b4, a0, a1, a2, a3, a4);
    if (hf == 0) {
      float* pc = cp + ((size_t)(col0 + c) * 64 + tr) * 5;
      pc[0] = a0; pc[1] = a1; pc[2] = a2; pc[3] = a3; pc[4] = a4;
    }
  }
}

// ---------- K4: merge partials (wave per line) + loss ----------
// rows: 32 partials (160 floats); cols: 64 partials (320 floats).
// Non-atomic, non-fenced: per-line loss to lossbuf; separate k_reduce sums.
// (R13: 2048 same-address atomics ~25-30 us; R15: per-block __threadfence
// ~137 us cross-XCD — both far worse than the ~2 us extra launch.)
__global__ __launch_bounds__(256) void k_merge(const float* __restrict__ sim,
                                               const float* __restrict__ rp,
                                               const float* __restrict__ cp,
                                               float* __restrict__ lossbuf) {
  int wave = threadIdx.x >> 6, lane = threadIdx.x & 63;
  int wid = blockIdx.x * 4 + wave;
  bool isCol = wid >= BSZ;
  int line = isCol ? wid - BSZ : wid;

  float t0 = -1e30f, t1 = -1e30f, t2 = -1e30f, t3 = -1e30f, t4 = -1e30f;
  if (isCol) {
    const float* src = cp + (size_t)line * 320;
    ins5(src[lane], t0, t1, t2, t3, t4);
    ins5(src[lane + 64], t0, t1, t2, t3, t4);
    ins5(src[lane + 128], t0, t1, t2, t3, t4);
    ins5(src[lane + 192], t0, t1, t2, t3, t4);
    ins5(src[lane + 256], t0, t1, t2, t3, t4);
  } else {
    const float* src = rp + (size_t)line * 160;
    ins5(src[lane], t0, t1, t2, t3, t4);
    ins5(src[lane + 64], t0, t1, t2, t3, t4);
    if (lane < 32) ins5(src[lane + 128], t0, t1, t2, t3, t4);
  }

  float top[5];
  #pragma unroll
  for (int e = 0; e < 5; e++) {
    float m = t0;
    #pragma unroll
    for (int off = 32; off >= 1; off >>= 1) m = fmaxf(m, __shfl_xor(m, off));
    unsigned long long msk = __ballot(t0 == m);
    int owner = __ffsll(msk) - 1;
    if (lane == owner) { t0 = t1; t1 = t2; t2 = t3; t3 = t4; t4 = -1e30f; }
    top[e] = m;
  }

  if (lane == 0) {
    float pos = sim[(size_t)line * BSZ + line] / TEMP;
    float l0 = top[0] / TEMP, l1 = top[1] / TEMP, l2 = top[2] / TEMP,
          l3 = top[3] / TEMP, l4 = top[4] / TEMP;
    float mx = fmaxf(pos, fmaxf(fmaxf(l0, l1), fmaxf(fmaxf(l2, l3), l4)));
    float s = expf(pos - mx) + expf(l0 - mx) + expf(l1 - mx) +
              expf(l2 - mx) + expf(l3 - mx) + expf(l4 - mx);
    lossbuf[wid] = mx + logf(s) - pos;
  }
}

// ---------- K5: final reduction ----------
__global__ __launch_bounds__(256) void k_reduce(const float* __restrict__ losses,
                                                float* __restrict__ out) {
  int tid = threadIdx.x;
  float s = 0.f;
  for (int i = tid; i < 2 * BSZ; i += 256) s += losses[i];
  #pragma unroll
  for (int off = 32; off >= 1; off >>= 1) s += __shfl_xor(s, off);
  __shared__ float wss[4];
  if ((tid & 63) == 0) wss[tid >> 6] = s;
  __syncthreads();
  if (tid == 0) out[0] = (wss[0] + wss[1] + wss[2] + wss[3]) / (2.0f * BSZ);
}

// ---------- launcher ----------
extern "C" void kernel_launch(void* const* d_in, const int* in_sizes, int n_in,
                              void* d_out, int out_size, void* d_ws, size_t ws_size,
                              hipStream_t stream) {
  const float* text = (const float*)d_in[0];
  const float* table = (const float*)d_in[1];
  float* out = (float*)d_out;
  float* sim = out + 1;  // d_out = [loss, sim(4096x4096)]

  uint16_t* Zb = (uint16_t*)d_ws;
  uint16_t* Tb = Zb + (size_t)BSZ * DIM;
  float* lossbuf = (float*)(Tb + (size_t)BSZ * DIM);  // 2*BSZ floats

  // rp/cp alias the Zb/Tb region (dead after k_gemm; stream-ordered).
  float* rp = (float*)d_ws;                  // [4096][32][5]
  float* cp = rp + (size_t)BSZ * 32 * 5;     // [4096][64][5]

  k_norm<<<2 * BSZ, 192, 0, stream>>>(text, table, Tb, Zb);
  k_gemm<<<(BSZ / 256) * (BSZ / 256), 512, 131072, stream>>>(Zb, Tb, sim);
  k_tile<<<(BSZ / 64) * (BSZ / 128), 256, 32768, stream>>>(sim, rp, cp);
  k_merge<<<2 * BSZ / 4, 256, 0, stream>>>(sim, rp, cp, lossbuf);
  k_reduce<<<1, 256, 0, stream>>>(lossbuf, out);
}